// Round 3
// baseline (819.245 us; speedup 1.0000x reference)
//
#include <hip/hip_runtime.h>
#include <math.h>

// Problem constants: B=2, C=4, L=1024, CH=256, CW=1, F=256, H=8, D=32, EXP=4
// N = B*L = 2048 samples.
//
// Workspace layout (floats):
//   cst  [1024][16][2]                 cos/sin rope table          32768
//   qc   [3][4][2048][256]             conv outputs (q,k,v)      6291456
//   qh   [B][C][H][L][D]                                         2097152
//   kh   "                                                       2097152
//   vh   "                                                       2097152
//   aw   [N][C][256]  attention out in af layout                 2097152
//   ow   [N][C][256]  wo output                                  2097152
// total ~64.1 MB

#define SWZ(r) ((((r) >> 2) & 7) << 2)

__global__ __launch_bounds__(256) void rope_table_kernel(float* __restrict__ cst) {
  int idx = blockIdx.x * 256 + threadIdx.x;
  if (idx >= 1024 * 16) return;
  int l = idx >> 4, j = idx & 15;
  float invf = powf(10000.0f, -(float)j / 16.0f);
  float th = (float)l * invf;
  cst[2 * idx] = cosf(th);
  cst[2 * idx + 1] = sinf(th);
}

// one block per sample n: instance-norm (C=4, 256) + 3-tap conv -> qc
__global__ __launch_bounds__(256) void prep_kernel(
    const float* __restrict__ x, const float* __restrict__ g1, const float* __restrict__ b1,
    const float* __restrict__ wqc, const float* __restrict__ wkc, const float* __restrict__ wvc,
    float* __restrict__ qc)
{
  __shared__ float xs[4][256];
  __shared__ float ns[4][256];
  __shared__ float cw[3][48];
  __shared__ float stat[4][2];
  int n = blockIdx.x, b = n >> 10, l = n & 1023;
  int t = threadIdx.x;
#pragma unroll
  for (int c = 0; c < 4; ++c)
    xs[c][t] = x[(size_t)((b * 4 + c) * 1024 + l) * 256 + t];
  if (t < 48) {  // (o,i,kh) flattened; kw=1 only (CW=1 degenerate conv)
    cw[0][t] = wqc[t * 3 + 1];
    cw[1][t] = wkc[t * 3 + 1];
    cw[2][t] = wvc[t * 3 + 1];
  }
  __syncthreads();
  int w = t >> 6, lane = t & 63;
  {
    float s1 = 0.f, s2 = 0.f;
#pragma unroll
    for (int k = 0; k < 4; ++k) { float v = xs[w][lane + 64 * k]; s1 += v; s2 += v * v; }
#pragma unroll
    for (int m = 1; m < 64; m <<= 1) { s1 += __shfl_xor(s1, m, 64); s2 += __shfl_xor(s2, m, 64); }
    if (lane == 0) {
      float mean = s1 * (1.0f / 256.0f);
      float var = s2 * (1.0f / 256.0f) - mean * mean;
      stat[w][0] = mean; stat[w][1] = rsqrtf(var + 1e-5f);
    }
  }
  __syncthreads();
#pragma unroll
  for (int c = 0; c < 4; ++c)
    ns[c][t] = (xs[c][t] - stat[c][0]) * stat[c][1] * g1[c] + b1[c];
  __syncthreads();
  float lf[4], mf[4], rf[4];
#pragma unroll
  for (int c = 0; c < 4; ++c) {
    mf[c] = ns[c][t];
    lf[c] = (t > 0) ? ns[c][t - 1] : 0.f;
    rf[c] = (t < 255) ? ns[c][t + 1] : 0.f;
  }
#pragma unroll
  for (int p = 0; p < 3; ++p)
#pragma unroll
    for (int o = 0; o < 4; ++o) {
      float acc = 0.f;
#pragma unroll
      for (int i = 0; i < 4; ++i) {
        const float* wp = &cw[p][(o * 4 + i) * 3];
        acc += lf[i] * wp[0] + mf[i] * wp[1] + rf[i] * wp[2];
      }
      qc[(size_t)((p * 4 + o) * 2048 + n) * 256 + t] = acc;
    }
}

// Tiled fp32 GEMM: Y[n,g] = sum_f X[n,f]*W[g,f].  64x64 tile, 4x4 microtile.
// mode 0: z=(proj*4+c), X=qc slab, epilogue rotary(q,k)/plain(v) -> head layout
// mode 1: z=c, X=aw strided, out -> ow
__global__ __launch_bounds__(256) void pw_gemm_kernel(
    const float* __restrict__ Xall,
    const float* __restrict__ W0, const float* __restrict__ W1, const float* __restrict__ W2,
    float* __restrict__ O0, float* __restrict__ O1, float* __restrict__ O2,
    const float* __restrict__ cst, int mode)
{
  __shared__ float Xs[64][68];
  __shared__ float Ws[64][68];
  int t = threadIdx.x, tx = t & 15, ty = t >> 4;
  int m0 = blockIdx.x << 6, n0 = blockIdx.y << 6;
  int z = blockIdx.z;
  const float* X; const float* W; int ldx; int proj, c;
  if (mode == 0) {
    proj = z >> 2; c = z & 3;
    X = Xall + (size_t)z * 2048 * 256; ldx = 256;
    W = ((proj == 0) ? W0 : (proj == 1) ? W1 : W2) + (size_t)c * 65536;
  } else {
    proj = 3; c = z;
    X = Xall + (size_t)c * 256; ldx = 1024;
    W = W0 + (size_t)c * 65536;
  }
  float acc[4][4] = {};
  int rr = t >> 2, cb = (t & 3) << 4;
  for (int k0 = 0; k0 < 256; k0 += 64) {
#pragma unroll
    for (int q = 0; q < 4; ++q) {
      int col = cb + (q << 2);
      *(float4*)&Xs[rr][col ^ SWZ(rr)] = *(const float4*)&X[(size_t)(m0 + rr) * ldx + k0 + col];
      *(float4*)&Ws[rr][col ^ SWZ(rr)] = *(const float4*)&W[(size_t)(n0 + rr) * 256 + k0 + col];
    }
    __syncthreads();
#pragma unroll
    for (int kk = 0; kk < 64; kk += 4) {
      float4 xv[4], wv[4];
#pragma unroll
      for (int i = 0; i < 4; ++i) xv[i] = *(const float4*)&Xs[ty * 4 + i][kk ^ ((ty & 7) << 2)];
#pragma unroll
      for (int j = 0; j < 4; ++j) wv[j] = *(const float4*)&Ws[tx * 4 + j][kk ^ ((tx & 7) << 2)];
#pragma unroll
      for (int i = 0; i < 4; ++i)
#pragma unroll
        for (int j = 0; j < 4; ++j)
          acc[i][j] += xv[i].x * wv[j].x + xv[i].y * wv[j].y + xv[i].z * wv[j].z + xv[i].w * wv[j].w;
    }
    __syncthreads();
  }
  if (mode == 0) {
    float* outp = (proj == 0) ? O0 : (proj == 1) ? O1 : O2;
#pragma unroll
    for (int i = 0; i < 4; ++i) {
      int nn = m0 + ty * 4 + i, bb = nn >> 10, ll = nn & 1023;
      size_t base = (size_t)((bb * 4 + c) * 8) * 32768 + (size_t)ll * 32;
      if (proj < 2) {
#pragma unroll
        for (int j = 0; j < 4; j += 2) {
          int g = n0 + tx * 4 + j;
          int h = g >> 5, d = g & 31, jd = d >> 1;
          float cs = cst[(ll * 16 + jd) * 2], sn = cst[(ll * 16 + jd) * 2 + 1];
          float ve = acc[i][j], vo = acc[i][j + 1];
          outp[base + (size_t)h * 32768 + d] = ve * cs - vo * sn;
          outp[base + (size_t)h * 32768 + d + 1] = vo * cs + ve * sn;
        }
      } else {
#pragma unroll
        for (int j = 0; j < 4; ++j) {
          int g = n0 + tx * 4 + j;
          int h = g >> 5, d = g & 31;
          outp[base + (size_t)h * 32768 + d] = acc[i][j];
        }
      }
    }
  } else {
#pragma unroll
    for (int i = 0; i < 4; ++i) {
      int nn = m0 + ty * 4 + i;
#pragma unroll
      for (int j = 0; j < 4; ++j) {
        int g = n0 + tx * 4 + j;
        O0[(size_t)(nn * 4 + c) * 256 + g] = acc[i][j];
      }
    }
  }
}

// Flash-style attention per (head, 64-row tile). Also writes pre-softmax qk.
__global__ __launch_bounds__(256) void attn_kernel(
    const float* __restrict__ qh, const float* __restrict__ kh, const float* __restrict__ vh,
    const float* __restrict__ prev, float* __restrict__ qkout, float* __restrict__ aw)
{
  __shared__ float Qs[64][36];
  __shared__ float Ks[64][36];
  __shared__ float Vs[64][36];
  __shared__ float Pl[64][68];
  int t = threadIdx.x, tx = t & 15, ty = t >> 4;
  int tile = blockIdx.x, head = blockIdx.y;
  int b = head >> 5, c = (head >> 3) & 3, h = head & 7;
  const float* Q = qh + (size_t)head * 32768;
  const float* K = kh + (size_t)head * 32768;
  const float* V = vh + (size_t)head * 32768;
  const float* PR = prev + (size_t)head * 1048576;
  float* QK = qkout + (size_t)head * 1048576;
  int l0 = tile << 6;
  {
    int r = t >> 3, c4 = (t & 7) << 2;
#pragma unroll
    for (int p = 0; p < 2; ++p) {
      int r2 = r + p * 32;
      *(float4*)&Qs[r2][c4 ^ SWZ(r2)] = *(const float4*)&Q[(size_t)(l0 + r2) * 32 + c4];
    }
  }
  float mrow[4], lrow[4], oa[4][2];
#pragma unroll
  for (int i = 0; i < 4; ++i) { mrow[i] = -INFINITY; lrow[i] = 0.f; oa[i][0] = 0.f; oa[i][1] = 0.f; }

  for (int t0 = 0; t0 < 1024; t0 += 64) {
    {
      int r = t >> 3, c4 = (t & 7) << 2;
#pragma unroll
      for (int p = 0; p < 2; ++p) {
        int r2 = r + p * 32;
        *(float4*)&Ks[r2][c4 ^ SWZ(r2)] = *(const float4*)&K[(size_t)(t0 + r2) * 32 + c4];
        *(float4*)&Vs[r2][c4]           = *(const float4*)&V[(size_t)(t0 + r2) * 32 + c4];
      }
    }
    __syncthreads();
    float s[4][4] = {};
#pragma unroll
    for (int d0 = 0; d0 < 32; d0 += 4) {
      float4 qv[4], kv[4];
#pragma unroll
      for (int i = 0; i < 4; ++i) qv[i] = *(const float4*)&Qs[ty * 4 + i][d0 ^ ((ty & 7) << 2)];
#pragma unroll
      for (int j = 0; j < 4; ++j) kv[j] = *(const float4*)&Ks[tx * 4 + j][d0 ^ ((tx & 7) << 2)];
#pragma unroll
      for (int i = 0; i < 4; ++i)
#pragma unroll
        for (int j = 0; j < 4; ++j)
          s[i][j] += qv[i].x * kv[j].x + qv[i].y * kv[j].y + qv[i].z * kv[j].z + qv[i].w * kv[j].w;
    }
#pragma unroll
    for (int i = 0; i < 4; ++i) {
      int gr = l0 + ty * 4 + i;
      size_t off = (size_t)gr * 1024 + t0 + tx * 4;
      float4 pv = *(const float4*)&PR[off];
      float4 sv;
      sv.x = s[i][0] * 0.0625f + pv.x;
      sv.y = s[i][1] * 0.0625f + pv.y;
      sv.z = s[i][2] * 0.0625f + pv.z;
      sv.w = s[i][3] * 0.0625f + pv.w;
      *(float4*)&QK[off] = sv;
      float tm = fmaxf(fmaxf(sv.x, sv.y), fmaxf(sv.z, sv.w));
      tm = fmaxf(tm, __shfl_xor(tm, 1, 16));
      tm = fmaxf(tm, __shfl_xor(tm, 2, 16));
      tm = fmaxf(tm, __shfl_xor(tm, 4, 16));
      tm = fmaxf(tm, __shfl_xor(tm, 8, 16));
      float mnew = fmaxf(mrow[i], tm);
      float sc = __expf(mrow[i] - mnew);
      float p0 = __expf(sv.x - mnew);
      float p1 = __expf(sv.y - mnew);
      float p2 = __expf(sv.z - mnew);
      float p3 = __expf(sv.w - mnew);
      Pl[ty * 4 + i][tx * 4 + 0] = p0;
      Pl[ty * 4 + i][tx * 4 + 1] = p1;
      Pl[ty * 4 + i][tx * 4 + 2] = p2;
      Pl[ty * 4 + i][tx * 4 + 3] = p3;
      float ps = p0 + p1 + p2 + p3;
      ps += __shfl_xor(ps, 1, 16);
      ps += __shfl_xor(ps, 2, 16);
      ps += __shfl_xor(ps, 4, 16);
      ps += __shfl_xor(ps, 8, 16);
      lrow[i] = lrow[i] * sc + ps;
      oa[i][0] *= sc;
      oa[i][1] *= sc;
      mrow[i] = mnew;
    }
    __syncthreads();
#pragma unroll
    for (int m0 = 0; m0 < 64; m0 += 4) {
      float4 p4[4];
#pragma unroll
      for (int i = 0; i < 4; ++i) p4[i] = *(const float4*)&Pl[ty * 4 + i][m0];
#pragma unroll
      for (int mm = 0; mm < 4; ++mm) {
        float2 vv = *(const float2*)&Vs[m0 + mm][tx * 2];
#pragma unroll
        for (int i = 0; i < 4; ++i) {
          float pm = (mm == 0) ? p4[i].x : (mm == 1) ? p4[i].y : (mm == 2) ? p4[i].z : p4[i].w;
          oa[i][0] += pm * vv.x;
          oa[i][1] += pm * vv.y;
        }
      }
    }
    __syncthreads();
  }
#pragma unroll
  for (int i = 0; i < 4; ++i) {
    int gr = l0 + ty * 4 + i;
    int nn = b * 1024 + gr;
    float inv = 1.0f / lrow[i];
    size_t o = (size_t)(nn * 4 + c) * 256 + h * 32 + tx * 2;
    aw[o]     = oa[i][0] * inv;
    aw[o + 1] = oa[i][1] * inv;
  }
}

// concat-norm + MLP + depthwise-mix + residual; one block per sample
__global__ __launch_bounds__(256) void tail_kernel(
    const float* __restrict__ x, const float* __restrict__ ow,
    const float* __restrict__ g2, const float* __restrict__ b2,
    const float* __restrict__ w1, const float* __restrict__ w2, const float* __restrict__ wdw,
    float* __restrict__ hout)
{
  __shared__ float zs[8][256];
  __shared__ float stat[8][2];
  __shared__ float z1s[8][4];
  int n = blockIdx.x, b = n >> 10, l = n & 1023;
  int t = threadIdx.x;
  float xreg[4];
#pragma unroll
  for (int c = 0; c < 4; ++c) {
    float v = x[(size_t)((b * 4 + c) * 1024 + l) * 256 + t];
    xreg[c] = v;
    zs[c][t] = v;
    zs[c + 4][t] = ow[(size_t)(n * 4 + c) * 256 + t];
  }
  __syncthreads();
  int w = t >> 6, lane = t & 63;
  for (int cc = w; cc < 8; cc += 4) {
    float s1 = 0.f, s2 = 0.f;
#pragma unroll
    for (int k = 0; k < 4; ++k) { float v = zs[cc][lane + 64 * k]; s1 += v; s2 += v * v; }
#pragma unroll
    for (int m = 1; m < 64; m <<= 1) { s1 += __shfl_xor(s1, m, 64); s2 += __shfl_xor(s2, m, 64); }
    if (lane == 0) {
      float mean = s1 * (1.0f / 256.0f);
      float var = s2 * (1.0f / 256.0f) - mean * mean;
      stat[cc][0] = mean; stat[cc][1] = rsqrtf(var + 1e-5f);
    }
  }
  __syncthreads();
#pragma unroll
  for (int cc = 0; cc < 8; ++cc)
    zs[cc][t] = (zs[cc][t] - stat[cc][0]) * stat[cc][1] * g2[cc] + b2[cc];
  __syncthreads();
  for (int idx = w * 8; idx < w * 8 + 8; ++idx) {
    int cc = idx >> 2, e = idx & 3;
    float s = 0.f;
#pragma unroll
    for (int k = 0; k < 4; ++k) { int f = lane + 64 * k; s += zs[cc][f] * w1[(size_t)(cc * 4 + e) * 256 + f]; }
#pragma unroll
    for (int m = 1; m < 64; m <<= 1) s += __shfl_xor(s, m, 64);
    if (lane == 0) z1s[cc][e] = (s > 0.f) ? s : 0.01f * s;
  }
  __syncthreads();
  float z3[4] = {0.f, 0.f, 0.f, 0.f};
#pragma unroll
  for (int cc = 0; cc < 8; ++cc) {
    float4 wv = *(const float4*)&w2[(size_t)(cc * 256 + t) * 4];
    float z2v = z1s[cc][0] * wv.x + z1s[cc][1] * wv.y + z1s[cc][2] * wv.z + z1s[cc][3] * wv.w;
#pragma unroll
    for (int d = 0; d < 4; ++d) z3[d] += z2v * wdw[d * 8 + cc];
  }
#pragma unroll
  for (int d = 0; d < 4; ++d)
    hout[(size_t)((b * 4 + d) * 1024 + l) * 256 + t] = xreg[d] + z3[d];
}

extern "C" void kernel_launch(void* const* d_in, const int* in_sizes, int n_in,
                              void* d_out, int out_size, void* d_ws, size_t ws_size,
                              hipStream_t stream) {
  const float* x    = (const float*)d_in[0];
  const float* prev = (const float*)d_in[1];
  const float* g1   = (const float*)d_in[2];
  const float* b1   = (const float*)d_in[3];
  const float* wqc  = (const float*)d_in[4];
  const float* wkc  = (const float*)d_in[5];
  const float* wvc  = (const float*)d_in[6];
  const float* wqp  = (const float*)d_in[7];
  const float* wkp  = (const float*)d_in[8];
  const float* wvp  = (const float*)d_in[9];
  const float* wop  = (const float*)d_in[10];
  const float* g2   = (const float*)d_in[11];
  const float* b2   = (const float*)d_in[12];
  const float* w1p  = (const float*)d_in[13];
  const float* w2p  = (const float*)d_in[14];
  const float* wdw  = (const float*)d_in[15];

  float* outf  = (float*)d_out;
  float* houtp = outf;               // (B,C,L,CH,CW) = 2097152 floats
  float* qkp   = outf + 2097152;     // (B,C,H,L,L)   = 67108864 floats

  float* ws  = (float*)d_ws;
  float* cst = ws;                   // 32768
  float* qc  = cst + 32768;          // 6291456
  float* qhp = qc + 6291456;         // 2097152
  float* khp = qhp + 2097152;
  float* vhp = khp + 2097152;
  float* awp = vhp + 2097152;
  float* owp = awp + 2097152;

  hipLaunchKernelGGL(rope_table_kernel, dim3(64), dim3(256), 0, stream, cst);
  hipLaunchKernelGGL(prep_kernel, dim3(2048), dim3(256), 0, stream,
                     x, g1, b1, wqc, wkc, wvc, qc);
  hipLaunchKernelGGL(pw_gemm_kernel, dim3(32, 4, 12), dim3(256), 0, stream,
                     qc, wqp, wkp, wvp, qhp, khp, vhp, cst, 0);
  hipLaunchKernelGGL(attn_kernel, dim3(16, 64), dim3(256), 0, stream,
                     qhp, khp, vhp, prev, qkp, awp);
  hipLaunchKernelGGL(pw_gemm_kernel, dim3(32, 4, 4), dim3(256), 0, stream,
                     awp, wop, wop, wop, owp, owp, owp, cst, 1);
  hipLaunchKernelGGL(tail_kernel, dim3(2048), dim3(256), 0, stream,
                     x, owp, g2, b2, w1p, w2p, wdw, houtp);
}